// Round 8
// baseline (466.966 us; speedup 1.0000x reference)
//
#include <hip/hip_runtime.h>

// GGN fused — split-bf16 (3-term) MFMA, 2-launch version.
//   xi = x[i]
//   h1 = relu([x, xi] @ W_n2e.T + b_n2e)   -> xi-half folded into c1 (fp32)
//   h2 = relu(h1 @ W_e2e.T + b_e2e)
//   g  = sum_n adj[n] * h2[n]
//   h  = W_e2n @ g + b_e2n
//   out = xi + b_out + W_out @ [xi; h]
// GEMMs: v_mfma_f32_16x16x32_bf16, a=ah+al, b=bh+bl, acc += ah*bh+al*bh+ah*bl.
// Tail fused into main via last-block pattern (atomics for cross-XCD safety).

#define DIM 128
#define HID 256
#define BM  64
#define TPB 512
#define NB  512

typedef float  f32x4 __attribute__((ext_vector_type(4)));
typedef short  s16x8 __attribute__((ext_vector_type(8)));

__device__ __forceinline__ unsigned short f2bf(float f) {
    unsigned u = __float_as_uint(f);
    return (unsigned short)((u + 0x7FFFu + ((u >> 16) & 1u)) >> 16);
}
__device__ __forceinline__ float bf2f(unsigned short h) {
    return __uint_as_float(((unsigned)h) << 16);
}

#define MFMA_BF16(acc, a, b) \
    asm volatile("v_mfma_f32_16x16x32_bf16 %0, %1, %2, %0" \
                 : "+v"(acc) : "v"(a), "v"(b))

// LDS layout (bytes). X and H1 OVERLAP (X dead after bar2, H1 born after).
#define XH_OFF   0        // X hi  [64] rows x 256B
#define XL_OFF   16384    // X lo
#define H1H_OFF  0        // H1 hi [64] rows x 512B
#define H1L_OFF  32768    // H1 lo
#define ADJ_OFF  65536    // adj [64] f32
#define SM_BYTES 65792

// ---------------- prep: pack weights + c1 + zero counter -------------------
// B-frag for (ks, cb): lane l holds B[ks*32 + (l>>4)*8 + r][cb*16 + (l&15)],
// dst = ((ks*16+cb)*64 + l)*8 + r
__global__ void prep_kernel(const float* __restrict__ x,
                            const int* __restrict__ ip,
                            const float* __restrict__ Wn2e,
                            const float* __restrict__ bn2e,
                            const float* __restrict__ We2e,
                            short* __restrict__ W1h, short* __restrict__ W1l,
                            short* __restrict__ W2h, short* __restrict__ W2l,
                            float* __restrict__ c1, int* __restrict__ cnt) {
    if (blockIdx.x == 384) {   // c1 + counter
        int o = threadIdx.x;   // 0..255
        const float* xi = x + (size_t)(*ip) * DIM;
        const float* wr = Wn2e + (size_t)o * (2 * DIM) + DIM;
        float s = bn2e[o];
        #pragma unroll 8
        for (int k = 0; k < DIM; ++k) s = fmaf(wr[k], xi[k], s);
        c1[o] = s;
        if (o == 0) *cnt = 0;
        return;
    }
    int tid = blockIdx.x * 256 + threadIdx.x;   // 0..98303
    float w; int o, k; short *dh, *dl;
    if (tid < 32768) {            // W1: [o<256][k<128]
        o = tid >> 7; k = tid & 127;
        w = Wn2e[(size_t)o * 256 + k];
        dh = W1h; dl = W1l;
    } else {                      // W2: [o<256][k<256]
        int u = tid - 32768;
        o = u >> 8; k = u & 255;
        w = We2e[(size_t)o * 256 + k];
        dh = W2h; dl = W2l;
    }
    int ks = k >> 5, koff = k & 31;
    int lane = ((koff >> 3) << 4) | (o & 15);
    int cb = o >> 4;
    size_t dst = ((size_t)((ks * 16 + cb) * 64 + lane)) * 8 + (koff & 7);
    unsigned short h = f2bf(w);
    dh[dst] = (short)h;
    dl[dst] = (short)f2bf(w - bf2f(h));
}

// ---------------- main (+fused tail) ---------------------------------------
__global__ __launch_bounds__(TPB, 4)
void main_kernel(const float* __restrict__ x,
                 const float* __restrict__ adj,
                 const int* __restrict__ ip,
                 const short* __restrict__ W1h, const short* __restrict__ W1l,
                 const short* __restrict__ W2h, const short* __restrict__ W2l,
                 const float* __restrict__ c1, const float* __restrict__ b2,
                 const float* __restrict__ W_e2n, const float* __restrict__ b_e2n,
                 const float* __restrict__ W_out, const float* __restrict__ b_out,
                 float* __restrict__ P, int* __restrict__ cnt,
                 float* __restrict__ out, int n_nodes, int ntiles) {
    __shared__ __attribute__((aligned(16))) unsigned char sm[SM_BYTES];
    __shared__ int lastFlag;

    const int t  = threadIdx.x;
    const int l  = t & 63;
    const int w  = __builtin_amdgcn_readfirstlane(t >> 6);  // wave 0..7
    const int lc = l & 15;
    const int lg = l >> 4;

    float c1v[2], b2v[2];
    #pragma unroll
    for (int nf = 0; nf < 2; ++nf) {
        int col = w * 32 + nf * 16 + lc;
        c1v[nf] = c1[col];
        b2v[nf] = b2[col];
    }

    // per-wave B bases (s16x8 units): idx = (ks*16 + w*2+nf)*64 + l
    const s16x8* pW1h = (const s16x8*)W1h + (size_t)(w * 2) * 64 + l;
    const s16x8* pW1l = (const s16x8*)W1l + (size_t)(w * 2) * 64 + l;
    const s16x8* pW2h = (const s16x8*)W2h + (size_t)(w * 2) * 64 + l;
    const s16x8* pW2l = (const s16x8*)W2l + (size_t)(w * 2) * 64 + l;

    float spart[2] = {0.f, 0.f};
    const float4* xg4 = (const float4*)x;

    for (int tile = blockIdx.x; tile < ntiles; tile += gridDim.x) {
        const int bn = tile * BM;

        __syncthreads();   // bar0: prev GEMM2 done reading H1 (region reuse)

        // ---- stage X tile -> hi/lo bf16 in LDS (XOR-swizzled) ----
        #pragma unroll
        for (int j = 0; j < 4; ++j) {
            int f  = t + j * TPB;        // 0..2047
            int r  = f >> 5;
            int c4 = f & 31;
            int node = bn + r;
            float4 v = (node < n_nodes) ? xg4[(size_t)node * 32 + c4]
                                        : make_float4(0.f, 0.f, 0.f, 0.f);
            unsigned short h0 = f2bf(v.x), h1 = f2bf(v.y),
                           h2 = f2bf(v.z), h3 = f2bf(v.w);
            uint2 hu, lu;
            hu.x = (unsigned)h0 | ((unsigned)h1 << 16);
            hu.y = (unsigned)h2 | ((unsigned)h3 << 16);
            lu.x = (unsigned)f2bf(v.x - bf2f(h0)) |
                   ((unsigned)f2bf(v.y - bf2f(h1)) << 16);
            lu.y = (unsigned)f2bf(v.z - bf2f(h2)) |
                   ((unsigned)f2bf(v.w - bf2f(h3)) << 16);
            int cb = (c4 * 8) ^ ((r & 7) << 4);
            *(uint2*)(sm + XH_OFF + r * 256 + cb) = hu;
            *(uint2*)(sm + XL_OFF + r * 256 + cb) = lu;
        }
        if (t < BM) {
            int node = bn + t;
            *(float*)(sm + ADJ_OFF + t * 4) = (node < n_nodes) ? adj[node] : 0.f;
        }
        __syncthreads();   // bar1: X/adj staged

        // ---- GEMM1: K=128, 4 k-steps, B double-buffered from L2 ----
        f32x4 acc[4][2];
        #pragma unroll
        for (int mf = 0; mf < 4; ++mf)
            #pragma unroll
            for (int nf = 0; nf < 2; ++nf)
                acc[mf][nf] = (f32x4){0.f, 0.f, 0.f, 0.f};

        {
            s16x8 bh[2][2], bl[2][2];
            bh[0][0] = pW1h[0];  bh[0][1] = pW1h[64];
            bl[0][0] = pW1l[0];  bl[0][1] = pW1l[64];
            #pragma unroll
            for (int ks = 0; ks < 4; ++ks) {
                int cur = ks & 1, nxt = cur ^ 1;
                if (ks < 3) {
                    size_t off = (size_t)(ks + 1) * 1024;
                    bh[nxt][0] = pW1h[off];  bh[nxt][1] = pW1h[off + 64];
                    bl[nxt][0] = pW1l[off];  bl[nxt][1] = pW1l[off + 64];
                }
                s16x8 ah[4], al[4];
                #pragma unroll
                for (int mf = 0; mf < 4; ++mf) {
                    int row = mf * 16 + lc;
                    int cb = (ks * 64 + lg * 16) ^ ((row & 7) << 4);
                    ah[mf] = *(const s16x8*)(sm + XH_OFF + row * 256 + cb);
                    al[mf] = *(const s16x8*)(sm + XL_OFF + row * 256 + cb);
                }
                #pragma unroll
                for (int mf = 0; mf < 4; ++mf) {
                    MFMA_BF16(acc[mf][0], ah[mf], bh[cur][0]);
                    MFMA_BF16(acc[mf][1], ah[mf], bh[cur][1]);
                }
                #pragma unroll
                for (int mf = 0; mf < 4; ++mf) {
                    MFMA_BF16(acc[mf][0], al[mf], bh[cur][0]);
                    MFMA_BF16(acc[mf][1], al[mf], bh[cur][1]);
                }
                #pragma unroll
                for (int mf = 0; mf < 4; ++mf) {
                    MFMA_BF16(acc[mf][0], ah[mf], bl[cur][0]);
                    MFMA_BF16(acc[mf][1], ah[mf], bl[cur][1]);
                }
            }
        }

        __syncthreads();   // bar2: all waves done reading X -> region free
        asm volatile("s_nop 7\n\ts_nop 7\n\ts_nop 7" ::: );

        // ---- epilogue1: +c1, relu, cvt hi/lo, store H1 (swizzled) ----
        #pragma unroll
        for (int mf = 0; mf < 4; ++mf)
            #pragma unroll
            for (int nf = 0; nf < 2; ++nf) {
                int col = w * 32 + nf * 16 + lc;
                #pragma unroll
                for (int r = 0; r < 4; ++r) {
                    int row = mf * 16 + lg * 4 + r;
                    float v = fmaxf(acc[mf][nf][r] + c1v[nf], 0.f);
                    unsigned short h = f2bf(v);
                    unsigned short lo = f2bf(v - bf2f(h));
                    int cb = (col * 2) ^ ((row & 7) << 4);
                    *(unsigned short*)(sm + H1H_OFF + row * 512 + cb) = h;
                    *(unsigned short*)(sm + H1L_OFF + row * 512 + cb) = lo;
                }
            }
        __syncthreads();   // bar3: H1 visible

        // ---- GEMM2: K=256, 8 k-steps ----
        #pragma unroll
        for (int mf = 0; mf < 4; ++mf)
            #pragma unroll
            for (int nf = 0; nf < 2; ++nf)
                acc[mf][nf] = (f32x4){0.f, 0.f, 0.f, 0.f};

        {
            s16x8 bh[2][2], bl[2][2];
            bh[0][0] = pW2h[0];  bh[0][1] = pW2h[64];
            bl[0][0] = pW2l[0];  bl[0][1] = pW2l[64];
            #pragma unroll
            for (int ks = 0; ks < 8; ++ks) {
                int cur = ks & 1, nxt = cur ^ 1;
                if (ks < 7) {
                    size_t off = (size_t)(ks + 1) * 1024;
                    bh[nxt][0] = pW2h[off];  bh[nxt][1] = pW2h[off + 64];
                    bl[nxt][0] = pW2l[off];  bl[nxt][1] = pW2l[off + 64];
                }
                s16x8 ah[4], al[4];
                #pragma unroll
                for (int mf = 0; mf < 4; ++mf) {
                    int row = mf * 16 + lc;
                    int cb = (ks * 64 + lg * 16) ^ ((row & 7) << 4);
                    ah[mf] = *(const s16x8*)(sm + H1H_OFF + row * 512 + cb);
                    al[mf] = *(const s16x8*)(sm + H1L_OFF + row * 512 + cb);
                }
                #pragma unroll
                for (int mf = 0; mf < 4; ++mf) {
                    MFMA_BF16(acc[mf][0], ah[mf], bh[cur][0]);
                    MFMA_BF16(acc[mf][1], ah[mf], bh[cur][1]);
                }
                #pragma unroll
                for (int mf = 0; mf < 4; ++mf) {
                    MFMA_BF16(acc[mf][0], al[mf], bh[cur][0]);
                    MFMA_BF16(acc[mf][1], al[mf], bh[cur][1]);
                }
                #pragma unroll
                for (int mf = 0; mf < 4; ++mf) {
                    MFMA_BF16(acc[mf][0], ah[mf], bl[cur][0]);
                    MFMA_BF16(acc[mf][1], ah[mf], bl[cur][1]);
                }
            }
        }

        asm volatile("s_nop 7\n\ts_nop 7\n\ts_nop 7" ::: );

        // ---- epilogue2: +b2, relu, * adj[row], accumulate g-partials ----
        #pragma unroll
        for (int mf = 0; mf < 4; ++mf)
            #pragma unroll
            for (int r = 0; r < 4; ++r) {
                int row = mf * 16 + lg * 4 + r;
                float adv = *(const float*)(sm + ADJ_OFF + row * 4);
                #pragma unroll
                for (int nf = 0; nf < 2; ++nf)
                    spart[nf] += fmaxf(acc[mf][nf][r] + b2v[nf], 0.f) * adv;
            }
    }

    // ---- reduce g-partials, publish P (atomic stores: cross-XCD safe) ----
    #pragma unroll
    for (int nf = 0; nf < 2; ++nf) {
        float s = spart[nf];
        s += __shfl_xor(s, 16);
        s += __shfl_xor(s, 32);
        if (l < 16)
            atomicExch(&P[(size_t)blockIdx.x * HID + w * 32 + nf * 16 + l], s);
    }

    // ---- last-block tail ----
    __threadfence();
    if (t == 0) lastFlag = (atomicAdd(cnt, 1) == (int)gridDim.x - 1);
    __syncthreads();
    if (!lastFlag) return;
    __threadfence();

    float* smf = (float*)sm;
    {   // g[o] = sum_b P[b][o]; two thread-halves then combine
        float s = 0.f;
        int o = t & 255, half = t >> 8;
        for (int b = half; b < (int)gridDim.x; b += 2)
            s += atomicAdd(&P[(size_t)b * HID + o], 0.f);   // coherent read
        smf[t] = s;
    }
    __syncthreads();
    if (t < HID) smf[t] += smf[t + HID];
    __syncthreads();
    if (t < HID) {   // h = W_e2n @ g + b_e2n
        const float* wr = W_e2n + (size_t)t * HID;
        float h = b_e2n[t];
        #pragma unroll 8
        for (int k = 0; k < HID; ++k) h = fmaf(wr[k], smf[k], h);
        smf[HID + t] = h;
    }
    __syncthreads();
    if (t < DIM) {
        const float* xi = x + (size_t)(*ip) * DIM;
        const float* wo = W_out + (size_t)t * (DIM + HID);
        float v = b_out[t] + xi[t];
        #pragma unroll 8
        for (int k = 0; k < DIM; ++k) v = fmaf(wo[k], xi[k], v);
        #pragma unroll 8
        for (int k = 0; k < HID; ++k) v = fmaf(wo[DIM + k], smf[HID + k], v);
        out[t] = v;
    }
}

extern "C" void kernel_launch(void* const* d_in, const int* in_sizes, int n_in,
                              void* d_out, int out_size, void* d_ws, size_t ws_size,
                              hipStream_t stream) {
    const float* x     = (const float*)d_in[0];
    const float* adj   = (const float*)d_in[1];
    const int*   ip    = (const int*)d_in[2];
    const float* W_n2e = (const float*)d_in[3];
    const float* b_n2e = (const float*)d_in[4];
    const float* W_e2e = (const float*)d_in[5];
    const float* b_e2e = (const float*)d_in[6];
    const float* W_e2n = (const float*)d_in[7];
    const float* b_e2n = (const float*)d_in[8];
    const float* W_out = (const float*)d_in[9];
    const float* b_out = (const float*)d_in[10];
    float* out = (float*)d_out;

    const int n_nodes = in_sizes[1];
    const int ntiles  = (n_nodes + BM - 1) / BM;

    // ws: W1h[32768] W1l[32768] W2h[65536] W2l[65536] shorts | c1[256] f32 |
    //     P[NB*256] f32 | cnt int
    short* W1h = (short*)d_ws;
    short* W1l = W1h + 32768;
    short* W2h = W1l + 32768;
    short* W2l = W2h + 65536;
    float* c1  = (float*)(W2l + 65536);
    float* P   = c1 + HID;
    int*   cnt = (int*)(P + (size_t)NB * HID);

    prep_kernel<<<385, 256, 0, stream>>>(x, ip, W_n2e, b_n2e, W_e2e,
                                         W1h, W1l, W2h, W2l, c1, cnt);
    main_kernel<<<NB, TPB, 0, stream>>>(x, adj, ip, W1h, W1l, W2h, W2l,
                                        c1, b_e2e, W_e2n, b_e2n, W_out, b_out,
                                        P, cnt, out, n_nodes, ntiles);
}

// Round 11
// 325.828 us; speedup vs baseline: 1.4332x; 1.4332x over previous
//
#include <hip/hip_runtime.h>

// GGN fused — split-bf16 (3-term) MFMA, 2-launch version.
//   xi = x[i]
//   h1 = relu([x, xi] @ W_n2e.T + b_n2e)   -> xi-half folded into c1 (fp32)
//   h2 = relu(h1 @ W_e2e.T + b_e2e)
//   g  = sum_n adj[n] * h2[n]
//   h  = W_e2n @ g + b_e2n
//   out = xi + b_out + W_out @ [xi; h]
// GEMMs: v_mfma_f32_16x16x32_bf16, a=ah+al, b=bh+bl, acc += ah*bh+al*bh+ah*bl.
// Tail fused into main via last-block pattern (atomics for cross-XCD safety).
// R8 lesson: __launch_bounds__(512,4) forced 64 VGPR -> massive scratch spill
// (FETCH 261MB/WRITE 156MB). Now (512,2): VGPR free to ~128, occupancy is
// LDS-capped at 2 blocks/CU (64.5KB each).

#define DIM 128
#define HID 256
#define BM  64
#define TPB 512
#define NB  512

typedef float  f32x4 __attribute__((ext_vector_type(4)));
typedef short  s16x8 __attribute__((ext_vector_type(8)));

__device__ __forceinline__ unsigned short f2bf(float f) {
    unsigned u = __float_as_uint(f);
    return (unsigned short)((u + 0x7FFFu + ((u >> 16) & 1u)) >> 16);
}
__device__ __forceinline__ float bf2f(unsigned short h) {
    return __uint_as_float(((unsigned)h) << 16);
}

#define MFMA_BF16(acc, a, b) \
    asm volatile("v_mfma_f32_16x16x32_bf16 %0, %1, %2, %0" \
                 : "+v"(acc) : "v"(a), "v"(b))

// LDS layout (bytes). X and H1 OVERLAP (X dead after bar2, H1 born after).
#define XH_OFF   0        // X hi  [64] rows x 256B
#define XL_OFF   16384    // X lo
#define H1H_OFF  0        // H1 hi [64] rows x 512B
#define H1L_OFF  32768    // H1 lo
#define ADJ_OFF  65536    // adj [64] f32
#define SM_BYTES 65792

// ---------------- prep: pack weights + c1 + zero counter -------------------
// B-frag for (ks, cb): lane l holds B[ks*32 + (l>>4)*8 + r][cb*16 + (l&15)],
// dst = ((ks*16+cb)*64 + l)*8 + r
__global__ void prep_kernel(const float* __restrict__ x,
                            const int* __restrict__ ip,
                            const float* __restrict__ Wn2e,
                            const float* __restrict__ bn2e,
                            const float* __restrict__ We2e,
                            short* __restrict__ W1h, short* __restrict__ W1l,
                            short* __restrict__ W2h, short* __restrict__ W2l,
                            float* __restrict__ c1, int* __restrict__ cnt) {
    if (blockIdx.x == 384) {   // c1 + counter
        int o = threadIdx.x;   // 0..255
        const float* xi = x + (size_t)(*ip) * DIM;
        const float* wr = Wn2e + (size_t)o * (2 * DIM) + DIM;
        float s = bn2e[o];
        #pragma unroll 8
        for (int k = 0; k < DIM; ++k) s = fmaf(wr[k], xi[k], s);
        c1[o] = s;
        if (o == 0) *cnt = 0;
        return;
    }
    int tid = blockIdx.x * 256 + threadIdx.x;   // 0..98303
    float w; int o, k; short *dh, *dl;
    if (tid < 32768) {            // W1: [o<256][k<128]
        o = tid >> 7; k = tid & 127;
        w = Wn2e[(size_t)o * 256 + k];
        dh = W1h; dl = W1l;
    } else {                      // W2: [o<256][k<256]
        int u = tid - 32768;
        o = u >> 8; k = u & 255;
        w = We2e[(size_t)o * 256 + k];
        dh = W2h; dl = W2l;
    }
    int ks = k >> 5, koff = k & 31;
    int lane = ((koff >> 3) << 4) | (o & 15);
    int cb = o >> 4;
    size_t dst = ((size_t)((ks * 16 + cb) * 64 + lane)) * 8 + (koff & 7);
    unsigned short h = f2bf(w);
    dh[dst] = (short)h;
    dl[dst] = (short)f2bf(w - bf2f(h));
}

// ---------------- main (+fused tail) ---------------------------------------
__global__ __launch_bounds__(TPB, 2)
void main_kernel(const float* __restrict__ x,
                 const float* __restrict__ adj,
                 const int* __restrict__ ip,
                 const short* __restrict__ W1h, const short* __restrict__ W1l,
                 const short* __restrict__ W2h, const short* __restrict__ W2l,
                 const float* __restrict__ c1, const float* __restrict__ b2,
                 const float* __restrict__ W_e2n, const float* __restrict__ b_e2n,
                 const float* __restrict__ W_out, const float* __restrict__ b_out,
                 float* __restrict__ P, int* __restrict__ cnt,
                 float* __restrict__ out, int n_nodes, int ntiles) {
    __shared__ __attribute__((aligned(16))) unsigned char sm[SM_BYTES];
    __shared__ int lastFlag;

    const int t  = threadIdx.x;
    const int l  = t & 63;
    const int w  = __builtin_amdgcn_readfirstlane(t >> 6);  // wave 0..7
    const int lc = l & 15;
    const int lg = l >> 4;

    float c1v[2], b2v[2];
    #pragma unroll
    for (int nf = 0; nf < 2; ++nf) {
        int col = w * 32 + nf * 16 + lc;
        c1v[nf] = c1[col];
        b2v[nf] = b2[col];
    }

    // per-wave B bases (s16x8 units): idx = (ks*16 + w*2+nf)*64 + l
    const s16x8* pW1h = (const s16x8*)W1h + (size_t)(w * 2) * 64 + l;
    const s16x8* pW1l = (const s16x8*)W1l + (size_t)(w * 2) * 64 + l;
    const s16x8* pW2h = (const s16x8*)W2h + (size_t)(w * 2) * 64 + l;
    const s16x8* pW2l = (const s16x8*)W2l + (size_t)(w * 2) * 64 + l;

    float spart[2] = {0.f, 0.f};
    const float4* xg4 = (const float4*)x;

    for (int tile = blockIdx.x; tile < ntiles; tile += gridDim.x) {
        const int bn = tile * BM;

        __syncthreads();   // bar0: prev GEMM2 done reading H1 (region reuse)

        // ---- stage X tile -> hi/lo bf16 in LDS (XOR-swizzled) ----
        #pragma unroll
        for (int j = 0; j < 4; ++j) {
            int f  = t + j * TPB;        // 0..2047
            int r  = f >> 5;
            int c4 = f & 31;
            int node = bn + r;
            float4 v = (node < n_nodes) ? xg4[(size_t)node * 32 + c4]
                                        : make_float4(0.f, 0.f, 0.f, 0.f);
            unsigned short h0 = f2bf(v.x), h1 = f2bf(v.y),
                           h2 = f2bf(v.z), h3 = f2bf(v.w);
            uint2 hu, lu;
            hu.x = (unsigned)h0 | ((unsigned)h1 << 16);
            hu.y = (unsigned)h2 | ((unsigned)h3 << 16);
            lu.x = (unsigned)f2bf(v.x - bf2f(h0)) |
                   ((unsigned)f2bf(v.y - bf2f(h1)) << 16);
            lu.y = (unsigned)f2bf(v.z - bf2f(h2)) |
                   ((unsigned)f2bf(v.w - bf2f(h3)) << 16);
            int cb = (c4 * 8) ^ ((r & 7) << 4);
            *(uint2*)(sm + XH_OFF + r * 256 + cb) = hu;
            *(uint2*)(sm + XL_OFF + r * 256 + cb) = lu;
        }
        if (t < BM) {
            int node = bn + t;
            *(float*)(sm + ADJ_OFF + t * 4) = (node < n_nodes) ? adj[node] : 0.f;
        }
        __syncthreads();   // bar1: X/adj staged

        // ---- GEMM1: K=128, 4 k-steps, B double-buffered from L2 ----
        f32x4 acc[4][2];
        #pragma unroll
        for (int mf = 0; mf < 4; ++mf)
            #pragma unroll
            for (int nf = 0; nf < 2; ++nf)
                acc[mf][nf] = (f32x4){0.f, 0.f, 0.f, 0.f};

        {
            s16x8 bh[2][2], bl[2][2];
            bh[0][0] = pW1h[0];  bh[0][1] = pW1h[64];
            bl[0][0] = pW1l[0];  bl[0][1] = pW1l[64];
            #pragma unroll
            for (int ks = 0; ks < 4; ++ks) {
                int cur = ks & 1, nxt = cur ^ 1;
                if (ks < 3) {
                    size_t off = (size_t)(ks + 1) * 1024;
                    bh[nxt][0] = pW1h[off];  bh[nxt][1] = pW1h[off + 64];
                    bl[nxt][0] = pW1l[off];  bl[nxt][1] = pW1l[off + 64];
                }
                s16x8 ah[4], al[4];
                #pragma unroll
                for (int mf = 0; mf < 4; ++mf) {
                    int row = mf * 16 + lc;
                    int cb = (ks * 64 + lg * 16) ^ ((row & 7) << 4);
                    ah[mf] = *(const s16x8*)(sm + XH_OFF + row * 256 + cb);
                    al[mf] = *(const s16x8*)(sm + XL_OFF + row * 256 + cb);
                }
                #pragma unroll
                for (int mf = 0; mf < 4; ++mf) {
                    MFMA_BF16(acc[mf][0], ah[mf], bh[cur][0]);
                    MFMA_BF16(acc[mf][1], ah[mf], bh[cur][1]);
                }
                #pragma unroll
                for (int mf = 0; mf < 4; ++mf) {
                    MFMA_BF16(acc[mf][0], al[mf], bh[cur][0]);
                    MFMA_BF16(acc[mf][1], al[mf], bh[cur][1]);
                }
                #pragma unroll
                for (int mf = 0; mf < 4; ++mf) {
                    MFMA_BF16(acc[mf][0], ah[mf], bl[cur][0]);
                    MFMA_BF16(acc[mf][1], ah[mf], bl[cur][1]);
                }
            }
        }

        __syncthreads();   // bar2: all waves done reading X -> region free
        asm volatile("s_nop 7\n\ts_nop 7\n\ts_nop 7" ::: );

        // ---- epilogue1: +c1, relu, cvt hi/lo, store H1 (swizzled) ----
        #pragma unroll
        for (int mf = 0; mf < 4; ++mf)
            #pragma unroll
            for (int nf = 0; nf < 2; ++nf) {
                int col = w * 32 + nf * 16 + lc;
                #pragma unroll
                for (int r = 0; r < 4; ++r) {
                    int row = mf * 16 + lg * 4 + r;
                    float v = fmaxf(acc[mf][nf][r] + c1v[nf], 0.f);
                    unsigned short h = f2bf(v);
                    unsigned short lo = f2bf(v - bf2f(h));
                    int cb = (col * 2) ^ ((row & 7) << 4);
                    *(unsigned short*)(sm + H1H_OFF + row * 512 + cb) = h;
                    *(unsigned short*)(sm + H1L_OFF + row * 512 + cb) = lo;
                }
            }
        __syncthreads();   // bar3: H1 visible

        // ---- GEMM2: K=256, 8 k-steps ----
        #pragma unroll
        for (int mf = 0; mf < 4; ++mf)
            #pragma unroll
            for (int nf = 0; nf < 2; ++nf)
                acc[mf][nf] = (f32x4){0.f, 0.f, 0.f, 0.f};

        {
            s16x8 bh[2][2], bl[2][2];
            bh[0][0] = pW2h[0];  bh[0][1] = pW2h[64];
            bl[0][0] = pW2l[0];  bl[0][1] = pW2l[64];
            #pragma unroll
            for (int ks = 0; ks < 8; ++ks) {
                int cur = ks & 1, nxt = cur ^ 1;
                if (ks < 7) {
                    size_t off = (size_t)(ks + 1) * 1024;
                    bh[nxt][0] = pW2h[off];  bh[nxt][1] = pW2h[off + 64];
                    bl[nxt][0] = pW2l[off];  bl[nxt][1] = pW2l[off + 64];
                }
                s16x8 ah[4], al[4];
                #pragma unroll
                for (int mf = 0; mf < 4; ++mf) {
                    int row = mf * 16 + lc;
                    int cb = (ks * 64 + lg * 16) ^ ((row & 7) << 4);
                    ah[mf] = *(const s16x8*)(sm + H1H_OFF + row * 512 + cb);
                    al[mf] = *(const s16x8*)(sm + H1L_OFF + row * 512 + cb);
                }
                #pragma unroll
                for (int mf = 0; mf < 4; ++mf) {
                    MFMA_BF16(acc[mf][0], ah[mf], bh[cur][0]);
                    MFMA_BF16(acc[mf][1], ah[mf], bh[cur][1]);
                }
                #pragma unroll
                for (int mf = 0; mf < 4; ++mf) {
                    MFMA_BF16(acc[mf][0], al[mf], bh[cur][0]);
                    MFMA_BF16(acc[mf][1], al[mf], bh[cur][1]);
                }
                #pragma unroll
                for (int mf = 0; mf < 4; ++mf) {
                    MFMA_BF16(acc[mf][0], ah[mf], bl[cur][0]);
                    MFMA_BF16(acc[mf][1], ah[mf], bl[cur][1]);
                }
            }
        }

        asm volatile("s_nop 7\n\ts_nop 7\n\ts_nop 7" ::: );

        // ---- epilogue2: +b2, relu, * adj[row], accumulate g-partials ----
        #pragma unroll
        for (int mf = 0; mf < 4; ++mf)
            #pragma unroll
            for (int r = 0; r < 4; ++r) {
                int row = mf * 16 + lg * 4 + r;
                float adv = *(const float*)(sm + ADJ_OFF + row * 4);
                #pragma unroll
                for (int nf = 0; nf < 2; ++nf)
                    spart[nf] += fmaxf(acc[mf][nf][r] + b2v[nf], 0.f) * adv;
            }
    }

    // ---- reduce g-partials, publish P (atomic stores: cross-XCD safe) ----
    #pragma unroll
    for (int nf = 0; nf < 2; ++nf) {
        float s = spart[nf];
        s += __shfl_xor(s, 16);
        s += __shfl_xor(s, 32);
        if (l < 16)
            atomicExch(&P[(size_t)blockIdx.x * HID + w * 32 + nf * 16 + l], s);
    }

    // ---- last-block tail ----
    __threadfence();
    if (t == 0) lastFlag = (atomicAdd(cnt, 1) == (int)gridDim.x - 1);
    __syncthreads();
    if (!lastFlag) return;
    __threadfence();

    float* smf = (float*)sm;
    {   // g[o] = sum_b P[b][o]; two thread-halves then combine
        float s = 0.f;
        int o = t & 255, half = t >> 8;
        for (int b = half; b < (int)gridDim.x; b += 2)
            s += atomicAdd(&P[(size_t)b * HID + o], 0.f);   // coherent read
        smf[t] = s;
    }
    __syncthreads();
    if (t < HID) smf[t] += smf[t + HID];
    __syncthreads();
    if (t < HID) {   // h = W_e2n @ g + b_e2n
        const float* wr = W_e2n + (size_t)t * HID;
        float h = b_e2n[t];
        #pragma unroll 8
        for (int k = 0; k < HID; ++k) h = fmaf(wr[k], smf[k], h);
        smf[HID + t] = h;
    }
    __syncthreads();
    if (t < DIM) {
        const float* xi = x + (size_t)(*ip) * DIM;
        const float* wo = W_out + (size_t)t * (DIM + HID);
        float v = b_out[t] + xi[t];
        #pragma unroll 8
        for (int k = 0; k < DIM; ++k) v = fmaf(wo[k], xi[k], v);
        #pragma unroll 8
        for (int k = 0; k < HID; ++k) v = fmaf(wo[DIM + k], smf[HID + k], v);
        out[t] = v;
    }
}

extern "C" void kernel_launch(void* const* d_in, const int* in_sizes, int n_in,
                              void* d_out, int out_size, void* d_ws, size_t ws_size,
                              hipStream_t stream) {
    const float* x     = (const float*)d_in[0];
    const float* adj   = (const float*)d_in[1];
    const int*   ip    = (const int*)d_in[2];
    const float* W_n2e = (const float*)d_in[3];
    const float* b_n2e = (const float*)d_in[4];
    const float* W_e2e = (const float*)d_in[5];
    const float* b_e2e = (const float*)d_in[6];
    const float* W_e2n = (const float*)d_in[7];
    const float* b_e2n = (const float*)d_in[8];
    const float* W_out = (const float*)d_in[9];
    const float* b_out = (const float*)d_in[10];
    float* out = (float*)d_out;

    const int n_nodes = in_sizes[1];
    const int ntiles  = (n_nodes + BM - 1) / BM;

    // ws: W1h[32768] W1l[32768] W2h[65536] W2l[65536] shorts | c1[256] f32 |
    //     P[NB*256] f32 | cnt int
    short* W1h = (short*)d_ws;
    short* W1l = W1h + 32768;
    short* W2h = W1l + 32768;
    short* W2l = W2h + 65536;
    float* c1  = (float*)(W2l + 65536);
    float* P   = c1 + HID;
    int*   cnt = (int*)(P + (size_t)NB * HID);

    prep_kernel<<<385, 256, 0, stream>>>(x, ip, W_n2e, b_n2e, W_e2e,
                                         W1h, W1l, W2h, W2l, c1, cnt);
    main_kernel<<<NB, TPB, 0, stream>>>(x, adj, ip, W1h, W1l, W2h, W2l,
                                        c1, b_e2e, W_e2n, b_e2n, W_out, b_out,
                                        P, cnt, out, n_nodes, ntiles);
}

// Round 12
// 248.404 us; speedup vs baseline: 1.8799x; 1.3117x over previous
//
#include <hip/hip_runtime.h>

// GGN fused — split-bf16 (3-term) MFMA, 2-launch version.
//   xi = x[i]
//   h1 = relu([x, xi] @ W_n2e.T + b_n2e)   -> xi-half folded into c1 (fp32)
//   h2 = relu(h1 @ W_e2e.T + b_e2e)
//   g  = sum_n adj[n] * h2[n]
//   h  = W_e2n @ g + b_e2n
//   out = xi + b_out + W_out @ [xi; h]
// GEMMs: v_mfma_f32_16x16x32_bf16, a=ah+al, b=bh+bl, acc += ah*bh+al*bh+ah*bl.
// R8 lesson: launch_bounds (512,4) -> 64 VGPR -> spill. (512,2) -> 128 VGPR ok.
// R11 lesson: serial runtime-bound atomic tail (~53us GPU-idle) + unmeasured
// B-prefetch regression -> revert GEMM loops to R3-proven inline-B form,
// unroll tail atomics (compile-time NB bound).

#define DIM 128
#define HID 256
#define BM  64
#define TPB 512
#define NB  512

typedef float  f32x4 __attribute__((ext_vector_type(4)));
typedef short  s16x8 __attribute__((ext_vector_type(8)));

__device__ __forceinline__ unsigned short f2bf(float f) {
    unsigned u = __float_as_uint(f);
    return (unsigned short)((u + 0x7FFFu + ((u >> 16) & 1u)) >> 16);
}
__device__ __forceinline__ float bf2f(unsigned short h) {
    return __uint_as_float(((unsigned)h) << 16);
}

#define MFMA_BF16(acc, a, b) \
    asm volatile("v_mfma_f32_16x16x32_bf16 %0, %1, %2, %0" \
                 : "+v"(acc) : "v"(a), "v"(b))

// LDS layout (bytes). X and H1 OVERLAP (X dead after bar2, H1 born after).
#define XH_OFF   0        // X hi  [64] rows x 256B
#define XL_OFF   16384    // X lo
#define H1H_OFF  0        // H1 hi [64] rows x 512B
#define H1L_OFF  32768    // H1 lo
#define ADJ_OFF  65536    // adj [64] f32
#define SM_BYTES 65792

// ---------------- prep: pack weights + c1 + zero counter -------------------
// B-frag for (ks, cb): lane l holds B[ks*32 + (l>>4)*8 + r][cb*16 + (l&15)],
// dst = ((ks*16+cb)*64 + l)*8 + r
__global__ void prep_kernel(const float* __restrict__ x,
                            const int* __restrict__ ip,
                            const float* __restrict__ Wn2e,
                            const float* __restrict__ bn2e,
                            const float* __restrict__ We2e,
                            short* __restrict__ W1h, short* __restrict__ W1l,
                            short* __restrict__ W2h, short* __restrict__ W2l,
                            float* __restrict__ c1, int* __restrict__ cnt) {
    if (blockIdx.x == 384) {   // c1 + counter
        int o = threadIdx.x;   // 0..255
        const float* xi = x + (size_t)(*ip) * DIM;
        const float* wr = Wn2e + (size_t)o * (2 * DIM) + DIM;
        float s = bn2e[o];
        #pragma unroll 8
        for (int k = 0; k < DIM; ++k) s = fmaf(wr[k], xi[k], s);
        c1[o] = s;
        if (o == 0) *cnt = 0;
        return;
    }
    int tid = blockIdx.x * 256 + threadIdx.x;   // 0..98303
    float w; int o, k; short *dh, *dl;
    if (tid < 32768) {            // W1: [o<256][k<128]
        o = tid >> 7; k = tid & 127;
        w = Wn2e[(size_t)o * 256 + k];
        dh = W1h; dl = W1l;
    } else {                      // W2: [o<256][k<256]
        int u = tid - 32768;
        o = u >> 8; k = u & 255;
        w = We2e[(size_t)o * 256 + k];
        dh = W2h; dl = W2l;
    }
    int ks = k >> 5, koff = k & 31;
    int lane = ((koff >> 3) << 4) | (o & 15);
    int cb = o >> 4;
    size_t dst = ((size_t)((ks * 16 + cb) * 64 + lane)) * 8 + (koff & 7);
    unsigned short h = f2bf(w);
    dh[dst] = (short)h;
    dl[dst] = (short)f2bf(w - bf2f(h));
}

// ---------------- main (+fused tail) ---------------------------------------
__global__ __launch_bounds__(TPB, 2)
void main_kernel(const float* __restrict__ x,
                 const float* __restrict__ adj,
                 const int* __restrict__ ip,
                 const short* __restrict__ W1h, const short* __restrict__ W1l,
                 const short* __restrict__ W2h, const short* __restrict__ W2l,
                 const float* __restrict__ c1, const float* __restrict__ b2,
                 const float* __restrict__ W_e2n, const float* __restrict__ b_e2n,
                 const float* __restrict__ W_out, const float* __restrict__ b_out,
                 float* __restrict__ P, int* __restrict__ cnt,
                 float* __restrict__ out, int n_nodes, int ntiles) {
    __shared__ __attribute__((aligned(16))) unsigned char sm[SM_BYTES];
    __shared__ int lastFlag;

    const int t  = threadIdx.x;
    const int l  = t & 63;
    const int w  = __builtin_amdgcn_readfirstlane(t >> 6);  // wave 0..7
    const int lc = l & 15;
    const int lg = l >> 4;

    float c1v[2], b2v[2];
    #pragma unroll
    for (int nf = 0; nf < 2; ++nf) {
        int col = w * 32 + nf * 16 + lc;
        c1v[nf] = c1[col];
        b2v[nf] = b2[col];
    }

    float spart[2] = {0.f, 0.f};
    const float4* xg4 = (const float4*)x;

    for (int tile = blockIdx.x; tile < ntiles; tile += gridDim.x) {
        const int bn = tile * BM;

        __syncthreads();   // bar0: prev GEMM2 done reading H1 (region reuse)

        // ---- stage X tile -> hi/lo bf16 in LDS (XOR-swizzled) ----
        #pragma unroll
        for (int j = 0; j < 4; ++j) {
            int f  = t + j * TPB;        // 0..2047
            int r  = f >> 5;
            int c4 = f & 31;
            int node = bn + r;
            float4 v = (node < n_nodes) ? xg4[(size_t)node * 32 + c4]
                                        : make_float4(0.f, 0.f, 0.f, 0.f);
            unsigned short h0 = f2bf(v.x), h1 = f2bf(v.y),
                           h2 = f2bf(v.z), h3 = f2bf(v.w);
            uint2 hu, lu;
            hu.x = (unsigned)h0 | ((unsigned)h1 << 16);
            hu.y = (unsigned)h2 | ((unsigned)h3 << 16);
            lu.x = (unsigned)f2bf(v.x - bf2f(h0)) |
                   ((unsigned)f2bf(v.y - bf2f(h1)) << 16);
            lu.y = (unsigned)f2bf(v.z - bf2f(h2)) |
                   ((unsigned)f2bf(v.w - bf2f(h3)) << 16);
            int cb = (c4 * 8) ^ ((r & 7) << 4);
            *(uint2*)(sm + XH_OFF + r * 256 + cb) = hu;
            *(uint2*)(sm + XL_OFF + r * 256 + cb) = lu;
        }
        if (t < BM) {
            int node = bn + t;
            *(float*)(sm + ADJ_OFF + t * 4) = (node < n_nodes) ? adj[node] : 0.f;
        }
        __syncthreads();   // bar1: X/adj staged

        // ---- GEMM1: K=128, 4 k-steps, B loaded inline (R3-proven) ----
        f32x4 acc[4][2];
        #pragma unroll
        for (int mf = 0; mf < 4; ++mf)
            #pragma unroll
            for (int nf = 0; nf < 2; ++nf)
                acc[mf][nf] = (f32x4){0.f, 0.f, 0.f, 0.f};

        #pragma unroll
        for (int ks = 0; ks < 4; ++ks) {
            s16x8 ah[4], al[4];
            #pragma unroll
            for (int mf = 0; mf < 4; ++mf) {
                int row = mf * 16 + lc;
                int cb = (ks * 64 + lg * 16) ^ ((row & 7) << 4);
                ah[mf] = *(const s16x8*)(sm + XH_OFF + row * 256 + cb);
                al[mf] = *(const s16x8*)(sm + XL_OFF + row * 256 + cb);
            }
            s16x8 bh[2], bl[2];
            #pragma unroll
            for (int nf = 0; nf < 2; ++nf) {
                size_t bidx = ((size_t)((ks * 16 + (w * 2 + nf)) * 64 + l)) * 8;
                bh[nf] = *(const s16x8*)(W1h + bidx);
                bl[nf] = *(const s16x8*)(W1l + bidx);
            }
            #pragma unroll
            for (int mf = 0; mf < 4; ++mf)
                #pragma unroll
                for (int nf = 0; nf < 2; ++nf) {
                    MFMA_BF16(acc[mf][nf], ah[mf], bh[nf]);
                    MFMA_BF16(acc[mf][nf], al[mf], bh[nf]);
                    MFMA_BF16(acc[mf][nf], ah[mf], bl[nf]);
                }
        }

        __syncthreads();   // bar2: all waves done reading X -> region free
        asm volatile("s_nop 7\n\ts_nop 7\n\ts_nop 7" ::: );

        // ---- epilogue1: +c1, relu, cvt hi/lo, store H1 (swizzled) ----
        #pragma unroll
        for (int mf = 0; mf < 4; ++mf)
            #pragma unroll
            for (int nf = 0; nf < 2; ++nf) {
                int col = w * 32 + nf * 16 + lc;
                #pragma unroll
                for (int r = 0; r < 4; ++r) {
                    int row = mf * 16 + lg * 4 + r;
                    float v = fmaxf(acc[mf][nf][r] + c1v[nf], 0.f);
                    unsigned short h = f2bf(v);
                    unsigned short lo = f2bf(v - bf2f(h));
                    int cb = (col * 2) ^ ((row & 7) << 4);
                    *(unsigned short*)(sm + H1H_OFF + row * 512 + cb) = h;
                    *(unsigned short*)(sm + H1L_OFF + row * 512 + cb) = lo;
                }
            }
        __syncthreads();   // bar3: H1 visible

        // ---- GEMM2: K=256, 8 k-steps ----
        #pragma unroll
        for (int mf = 0; mf < 4; ++mf)
            #pragma unroll
            for (int nf = 0; nf < 2; ++nf)
                acc[mf][nf] = (f32x4){0.f, 0.f, 0.f, 0.f};

        #pragma unroll
        for (int ks = 0; ks < 8; ++ks) {
            s16x8 ah[4], al[4];
            #pragma unroll
            for (int mf = 0; mf < 4; ++mf) {
                int row = mf * 16 + lc;
                int cb = (ks * 64 + lg * 16) ^ ((row & 7) << 4);
                ah[mf] = *(const s16x8*)(sm + H1H_OFF + row * 512 + cb);
                al[mf] = *(const s16x8*)(sm + H1L_OFF + row * 512 + cb);
            }
            s16x8 bh[2], bl[2];
            #pragma unroll
            for (int nf = 0; nf < 2; ++nf) {
                size_t bidx = ((size_t)((ks * 16 + (w * 2 + nf)) * 64 + l)) * 8;
                bh[nf] = *(const s16x8*)(W2h + bidx);
                bl[nf] = *(const s16x8*)(W2l + bidx);
            }
            #pragma unroll
            for (int mf = 0; mf < 4; ++mf)
                #pragma unroll
                for (int nf = 0; nf < 2; ++nf) {
                    MFMA_BF16(acc[mf][nf], ah[mf], bh[nf]);
                    MFMA_BF16(acc[mf][nf], al[mf], bh[nf]);
                    MFMA_BF16(acc[mf][nf], ah[mf], bl[nf]);
                }
        }

        asm volatile("s_nop 7\n\ts_nop 7\n\ts_nop 7" ::: );

        // ---- epilogue2: +b2, relu, * adj[row], accumulate g-partials ----
        #pragma unroll
        for (int mf = 0; mf < 4; ++mf)
            #pragma unroll
            for (int r = 0; r < 4; ++r) {
                int row = mf * 16 + lg * 4 + r;
                float adv = *(const float*)(sm + ADJ_OFF + row * 4);
                #pragma unroll
                for (int nf = 0; nf < 2; ++nf)
                    spart[nf] += fmaxf(acc[mf][nf][r] + b2v[nf], 0.f) * adv;
            }
    }

    // ---- reduce g-partials, publish P (atomic stores: cross-XCD safe) ----
    #pragma unroll
    for (int nf = 0; nf < 2; ++nf) {
        float s = spart[nf];
        s += __shfl_xor(s, 16);
        s += __shfl_xor(s, 32);
        if (l < 16)
            atomicExch(&P[(size_t)blockIdx.x * HID + w * 32 + nf * 16 + l], s);
    }

    // ---- last-block tail ----
    __threadfence();
    if (t == 0) lastFlag = (atomicAdd(cnt, 1) == (int)gridDim.x - 1);
    __syncthreads();
    if (!lastFlag) return;
    __threadfence();

    float* smf = (float*)sm;
    {   // g[o] = sum_b P[b][o]; compile-time bound + unroll -> pipelined atomics
        float s = 0.f;
        int o = t & 255, half = t >> 8;
        #pragma unroll 8
        for (int b = half; b < NB; b += 2)
            s += atomicAdd(&P[(size_t)b * HID + o], 0.f);   // coherent read
        smf[t] = s;
    }
    __syncthreads();
    if (t < HID) smf[t] += smf[t + HID];
    __syncthreads();
    if (t < HID) {   // h = W_e2n @ g + b_e2n
        const float* wr = W_e2n + (size_t)t * HID;
        float h = b_e2n[t];
        #pragma unroll 8
        for (int k = 0; k < HID; ++k) h = fmaf(wr[k], smf[k], h);
        smf[HID + t] = h;
    }
    __syncthreads();
    if (t < DIM) {
        const float* xi = x + (size_t)(*ip) * DIM;
        const float* wo = W_out + (size_t)t * (DIM + HID);
        float v = b_out[t] + xi[t];
        #pragma unroll 8
        for (int k = 0; k < DIM; ++k) v = fmaf(wo[k], xi[k], v);
        #pragma unroll 8
        for (int k = 0; k < HID; ++k) v = fmaf(wo[DIM + k], smf[HID + k], v);
        out[t] = v;
    }
}

extern "C" void kernel_launch(void* const* d_in, const int* in_sizes, int n_in,
                              void* d_out, int out_size, void* d_ws, size_t ws_size,
                              hipStream_t stream) {
    const float* x     = (const float*)d_in[0];
    const float* adj   = (const float*)d_in[1];
    const int*   ip    = (const int*)d_in[2];
    const float* W_n2e = (const float*)d_in[3];
    const float* b_n2e = (const float*)d_in[4];
    const float* W_e2e = (const float*)d_in[5];
    const float* b_e2e = (const float*)d_in[6];
    const float* W_e2n = (const float*)d_in[7];
    const float* b_e2n = (const float*)d_in[8];
    const float* W_out = (const float*)d_in[9];
    const float* b_out = (const float*)d_in[10];
    float* out = (float*)d_out;

    const int n_nodes = in_sizes[1];
    const int ntiles  = (n_nodes + BM - 1) / BM;

    // ws: W1h[32768] W1l[32768] W2h[65536] W2l[65536] shorts | c1[256] f32 |
    //     P[NB*256] f32 | cnt int
    short* W1h = (short*)d_ws;
    short* W1l = W1h + 32768;
    short* W2h = W1l + 32768;
    short* W2l = W2h + 65536;
    float* c1  = (float*)(W2l + 65536);
    float* P   = c1 + HID;
    int*   cnt = (int*)(P + (size_t)NB * HID);

    prep_kernel<<<385, 256, 0, stream>>>(x, ip, W_n2e, b_n2e, W_e2e,
                                         W1h, W1l, W2h, W2l, c1, cnt);
    main_kernel<<<NB, TPB, 0, stream>>>(x, adj, ip, W1h, W1l, W2h, W2l,
                                        c1, b_e2e, W_e2n, b_e2n, W_out, b_out,
                                        P, cnt, out, n_nodes, ntiles);
}